// Round 1
// baseline (196.880 us; speedup 1.0000x reference)
//
#include <hip/hip_runtime.h>
#include <math.h>

#define L 250000
#define FEAT 100
#define HID 50
#define HS 165
#define CQ 50257
#define EXTV 1000
#define NOUT (CQ + EXTV)   // 51257
#define NB7 128

// workspace float offsets
#define WS_Q     0      // 100 floats (16B-aligned: offset 0)
#define WS_P1    100
#define WS_P2    101
#define WS_SCALE 102    // p2/denom
#define WS_DENOM 103
#define WS_CT    104    // 100
#define WS_ET    204    // 200
#define WS_H     404    // 50
#define WS_E     512    // 250000 (exp(score) per source position)
#define WS_OUT   250624 // 51257 (pre-logsoftmax extended vocab)
#define WS_PM    301952 // 128 partial maxes
#define WS_PS    302080 // 128 partial sums

__device__ __forceinline__ float sigm(float x) { return 1.f / (1.f + expf(-x)); }

// ---------------- K1: LSTM step + q + p1/p2 + accumulator init ----------------
__global__ void k1_lstm(const float* __restrict__ y, const float* __restrict__ h0,
                        const float* __restrict__ c0,
                        const float* __restrict__ W_ih, const float* __restrict__ W_hh,
                        const float* __restrict__ b_ih, const float* __restrict__ b_hh,
                        const float* __restrict__ w_h_W, const float* __restrict__ w_h_b,
                        const float* __restrict__ l3_W, const float* __restrict__ l3_b,
                        const float* __restrict__ l4_W, const float* __restrict__ l4_b,
                        float* __restrict__ ws, float* __restrict__ out) {
    __shared__ float s_y[HS], s_h[HID], s_c[HID], s_g[4 * HID], s_hn[HID];
    int t = threadIdx.x;
    if (t < HS) s_y[t] = y[t];
    if (t < HID) { s_h[t] = h0[t]; s_c[t] = c0[t]; }
    __syncthreads();
    if (t < 4 * HID) {
        float acc = b_ih[t] + b_hh[t];
        const float* wi = W_ih + t * HS;
        for (int k = 0; k < HS; ++k) acc += wi[k] * s_y[k];
        const float* wh = W_hh + t * HID;
        for (int k = 0; k < HID; ++k) acc += wh[k] * s_h[k];
        s_g[t] = acc;
    }
    __syncthreads();
    if (t < HID) {
        float ig = sigm(s_g[t]);
        float fg = sigm(s_g[HID + t]);
        float gg = tanhf(s_g[2 * HID + t]);
        float og = sigm(s_g[3 * HID + t]);
        float cn = fg * s_c[t] + ig * gg;
        float hn = og * tanhf(cn);
        s_hn[t] = hn;
        ws[WS_H + t] = hn;
        out[NOUT + t] = hn;          // h_new output
        out[NOUT + HID + t] = cn;    // c_new output
    }
    __syncthreads();
    if (t < FEAT) {
        float acc = w_h_b[t];
        const float* w = w_h_W + t * HID;
        for (int k = 0; k < HID; ++k) acc += w[k] * s_hn[k];
        ws[WS_Q + t] = acc;
        ws[WS_CT + t] = 0.f;         // zero context accumulator
    }
    if (t == 200) {
        float acc = l3_b[0];
        for (int k = 0; k < HID; ++k) acc += l3_W[k] * s_hn[k];
        ws[WS_P1] = sigm(acc);
    }
    if (t == 201) {
        float acc = l4_b[0];
        for (int k = 0; k < HID; ++k) acc += l4_W[k] * s_hn[k];
        ws[WS_P2] = sigm(acc);
    }
    if (t == 202) ws[WS_DENOM] = 0.f;
}

// ---------------- K2: scores e_i = exp(H_i . q), denom = sum e ----------------
__global__ void k2_scores(const float* __restrict__ H, const float* __restrict__ ws,
                          float* __restrict__ e_out, float* __restrict__ denom) {
    __shared__ float4 s_q[FEAT / 4];
    __shared__ float s_red[4];
    int t = threadIdx.x;
    if (t < FEAT / 4) s_q[t] = ((const float4*)(ws + WS_Q))[t];
    __syncthreads();
    int i = blockIdx.x * blockDim.x + t;
    float e = 0.f;
    if (i < L) {
        const float4* h4 = (const float4*)H + i * (FEAT / 4);
        float acc = 0.f;
#pragma unroll
        for (int j = 0; j < FEAT / 4; ++j) {
            float4 a = h4[j]; float4 b = s_q[j];
            acc += a.x * b.x + a.y * b.y + a.z * b.z + a.w * b.w;
        }
        e = expf(acc);               // scores bounded well below 88 -> maxless softmax exact
        e_out[i] = e;
    }
    for (int o = 32; o > 0; o >>= 1) e += __shfl_down(e, o);
    if ((t & 63) == 0) s_red[t >> 6] = e;
    __syncthreads();
    if (t == 0) atomicAdd(denom, s_red[0] + s_red[1] + s_red[2] + s_red[3]);
}

// ---------------- K3: ct[k] = sum_i e_i * H[i][k] ----------------
__global__ void k3_ct(const float* __restrict__ H, const float* __restrict__ e,
                      float* __restrict__ ct) {
    int t = threadIdx.x;
    int group = t >> 7;       // 0 or 1
    int lane = t & 127;
    int rows = (L + gridDim.x - 1) / gridDim.x;
    int start = blockIdx.x * rows;
    int end = min(start + rows, L);
    if (lane < FEAT && start < L) {
        float acc = 0.f;
        for (int i = start + group; i < end; i += 2)
            acc += e[i] * H[i * FEAT + lane];
        atomicAdd(&ct[lane], acc);
    }
}

// ---------------- K4: c_t /= denom ; e_t = sigmoid(l1) ; scale ----------------
__global__ void k4_et(const float* __restrict__ l1_W, const float* __restrict__ l1_b,
                      float* __restrict__ ws) {
    __shared__ float s_t[150];
    int t = threadIdx.x;
    float denom = ws[WS_DENOM];
    if (t < HID) s_t[t] = ws[WS_H + t];
    if (t < FEAT) s_t[HID + t] = ws[WS_CT + t] / denom;
    if (t == 0) ws[WS_SCALE] = ws[WS_P2] / denom;
    __syncthreads();
    if (t < 200) {
        float acc = l1_b[t];
        const float* w = l1_W + t * 150;
        for (int k = 0; k < 150; ++k) acc += w[k] * s_t[k];
        ws[WS_ET + t] = sigm(acc);
    }
}

// ---------------- K5: out[row] = p1*(l2_W[row].e_t + b) ; ext rows = 0 -------
__global__ void k5_vocab(const float* __restrict__ l2_W, const float* __restrict__ l2_b,
                         const float* __restrict__ ws, float* __restrict__ out) {
    __shared__ float s_e[200];
    __shared__ float s_p1;
    int t = threadIdx.x;
    if (t < 200) s_e[t] = ws[WS_ET + t];
    if (t == 255) s_p1 = ws[WS_P1];
    __syncthreads();
    int row = blockIdx.x * 4 + (t >> 6);
    int lane = t & 63;
    if (row < CQ) {
        const float* w = l2_W + row * 200;
        float acc = 0.f;
        for (int l = lane; l < 200; l += 64) acc += w[l] * s_e[l];
        for (int o = 32; o > 0; o >>= 1) acc += __shfl_down(acc, o);
        if (lane == 0) out[row] = s_p1 * (acc + l2_b[row]);
    } else if (row < NOUT) {
        if (lane == 0) out[row] = 0.f;
    }
}

// ---------------- K6: scatter-add pointer attention ----------------
__global__ void k6_scatter(const int* __restrict__ cont, const float* __restrict__ e,
                           const float* __restrict__ ws, float* __restrict__ out) {
    int i = blockIdx.x * blockDim.x + threadIdx.x;
    if (i < L) {
        float scale = ws[WS_SCALE];
        atomicAdd(&out[cont[i]], scale * e[i]);
    }
}

// ---------------- K7a: per-block max & sumexp partials ----------------
__global__ void k7a_partial(const float* __restrict__ outv, float* __restrict__ pm,
                            float* __restrict__ ps) {
    __shared__ float red[4];
    __shared__ float red2[4];
    int t = threadIdx.x;
    int chunk = (NOUT + gridDim.x - 1) / gridDim.x;
    int start = blockIdx.x * chunk;
    int end = min(start + chunk, NOUT);
    float m = -1e30f;
    for (int i = start + t; i < end; i += blockDim.x) m = fmaxf(m, outv[i]);
    for (int o = 32; o > 0; o >>= 1) m = fmaxf(m, __shfl_down(m, o));
    if ((t & 63) == 0) red[t >> 6] = m;
    __syncthreads();
    if (t == 0) red[0] = fmaxf(fmaxf(red[0], red[1]), fmaxf(red[2], red[3]));
    __syncthreads();
    m = red[0];
    float s = 0.f;
    for (int i = start + t; i < end; i += blockDim.x) s += expf(outv[i] - m);
    for (int o = 32; o > 0; o >>= 1) s += __shfl_down(s, o);
    if ((t & 63) == 0) red2[t >> 6] = s;
    __syncthreads();
    if (t == 0) { pm[blockIdx.x] = m; ps[blockIdx.x] = red2[0] + red2[1] + red2[2] + red2[3]; }
}

// ---------------- K7c: combine partials (redundant per thread) + final write --
__global__ void k7c_final(const float* __restrict__ outv, const float* __restrict__ pm,
                          const float* __restrict__ ps, float* __restrict__ dout) {
    int t = threadIdx.x;
    float gm = -1e30f;
    for (int b = 0; b < NB7; ++b) gm = fmaxf(gm, pm[b]);
    float s = 0.f;
    for (int b = 0; b < NB7; ++b) s += ps[b] * expf(pm[b] - gm);
    float lse = gm + logf(s);
    int j = blockIdx.x * blockDim.x + t;
    if (j < NOUT) dout[j] = outv[j] - lse;
}

extern "C" void kernel_launch(void* const* d_in, const int* in_sizes, int n_in,
                              void* d_out, int out_size, void* d_ws, size_t ws_size,
                              hipStream_t stream) {
    const float* H    = (const float*)d_in[0];
    const float* y    = (const float*)d_in[1];
    const float* h0   = (const float*)d_in[2];
    const float* c0   = (const float*)d_in[3];
    const int*   cont = (const int*)d_in[4];
    // d_in[5] = ext scalar (1000), hardcoded
    const float* W_ih = (const float*)d_in[6];
    const float* W_hh = (const float*)d_in[7];
    const float* b_ih = (const float*)d_in[8];
    const float* b_hh = (const float*)d_in[9];
    const float* w_h_W = (const float*)d_in[10];
    const float* w_h_b = (const float*)d_in[11];
    const float* l1_W = (const float*)d_in[12];
    const float* l1_b = (const float*)d_in[13];
    const float* l2_W = (const float*)d_in[14];
    const float* l2_b = (const float*)d_in[15];
    const float* l3_W = (const float*)d_in[16];
    const float* l3_b = (const float*)d_in[17];
    const float* l4_W = (const float*)d_in[18];
    const float* l4_b = (const float*)d_in[19];

    float* ws  = (float*)d_ws;
    float* out = (float*)d_out;

    k1_lstm<<<1, 256, 0, stream>>>(y, h0, c0, W_ih, W_hh, b_ih, b_hh,
                                   w_h_W, w_h_b, l3_W, l3_b, l4_W, l4_b, ws, out);

    k2_scores<<<(L + 255) / 256, 256, 0, stream>>>(H, ws, ws + WS_E, ws + WS_DENOM);

    k3_ct<<<1024, 256, 0, stream>>>(H, ws + WS_E, ws + WS_CT);

    k4_et<<<1, 256, 0, stream>>>(l1_W, l1_b, ws);

    k5_vocab<<<(NOUT + 3) / 4, 256, 0, stream>>>(l2_W, l2_b, ws, ws + WS_OUT);

    k6_scatter<<<(L + 255) / 256, 256, 0, stream>>>(cont, ws + WS_E, ws, ws + WS_OUT);

    k7a_partial<<<NB7, 256, 0, stream>>>(ws + WS_OUT, ws + WS_PM, ws + WS_PS);

    k7c_final<<<(NOUT + 255) / 256, 256, 0, stream>>>(ws + WS_OUT, ws + WS_PM, ws + WS_PS, out);
}

// Round 2
// 145.935 us; speedup vs baseline: 1.3491x; 1.3491x over previous
//
#include <hip/hip_runtime.h>
#include <math.h>

#define L 250000
#define FEAT 100
#define HID 50
#define HS 165
#define CQ 50257
#define EXTV 1000
#define NOUT (CQ + EXTV)   // 51257
#define NB7 128

// workspace float offsets
#define WS_Q     0      // 100 floats (16B-aligned: offset 0)
#define WS_P1    100
#define WS_P2    101
#define WS_SCALE 102    // p2/denom
#define WS_DENOM 103
#define WS_CT    104    // 100
#define WS_ET    204    // 200 (16B aligned: 204*4=816=51*16)
#define WS_H     404    // 50
#define WS_E     512    // 250000 (exp(score) per source position)
#define WS_OUT   250624 // 51257 (pre-logsoftmax extended vocab)
#define WS_PM    301952 // 128 partial maxes
#define WS_PS    302080 // 128 partial sums

__device__ __forceinline__ float sigm(float x) { return 1.f / (1.f + expf(-x)); }

// ---------------- K1: LSTM step + q + p1/p2 + accumulator init ----------------
__global__ void k1_lstm(const float* __restrict__ y, const float* __restrict__ h0,
                        const float* __restrict__ c0,
                        const float* __restrict__ W_ih, const float* __restrict__ W_hh,
                        const float* __restrict__ b_ih, const float* __restrict__ b_hh,
                        const float* __restrict__ w_h_W, const float* __restrict__ w_h_b,
                        const float* __restrict__ l3_W, const float* __restrict__ l3_b,
                        const float* __restrict__ l4_W, const float* __restrict__ l4_b,
                        float* __restrict__ ws, float* __restrict__ out) {
    __shared__ float s_y[HS], s_h[HID], s_c[HID], s_g[4 * HID], s_hn[HID];
    int t = threadIdx.x;
    if (t < HS) s_y[t] = y[t];
    if (t < HID) { s_h[t] = h0[t]; s_c[t] = c0[t]; }
    __syncthreads();
    if (t < 4 * HID) {
        float acc = b_ih[t] + b_hh[t];
        const float* wi = W_ih + t * HS;
        for (int k = 0; k < HS; ++k) acc += wi[k] * s_y[k];
        const float* wh = W_hh + t * HID;
        for (int k = 0; k < HID; ++k) acc += wh[k] * s_h[k];
        s_g[t] = acc;
    }
    __syncthreads();
    if (t < HID) {
        float ig = sigm(s_g[t]);
        float fg = sigm(s_g[HID + t]);
        float gg = tanhf(s_g[2 * HID + t]);
        float og = sigm(s_g[3 * HID + t]);
        float cn = fg * s_c[t] + ig * gg;
        float hn = og * tanhf(cn);
        s_hn[t] = hn;
        ws[WS_H + t] = hn;
        out[NOUT + t] = hn;          // h_new output
        out[NOUT + HID + t] = cn;    // c_new output
    }
    __syncthreads();
    if (t < FEAT) {
        float acc = w_h_b[t];
        const float* w = w_h_W + t * HID;
        for (int k = 0; k < HID; ++k) acc += w[k] * s_hn[k];
        ws[WS_Q + t] = acc;
        ws[WS_CT + t] = 0.f;         // zero context accumulator
    }
    if (t == 200) {
        float acc = l3_b[0];
        for (int k = 0; k < HID; ++k) acc += l3_W[k] * s_hn[k];
        ws[WS_P1] = sigm(acc);
    }
    if (t == 201) {
        float acc = l4_b[0];
        for (int k = 0; k < HID; ++k) acc += l4_W[k] * s_hn[k];
        ws[WS_P2] = sigm(acc);
    }
    if (t == 202) ws[WS_DENOM] = 0.f;
}

// ------- K23: single pass over H: e_i = exp(H_i.q); ct += e_i*H_i; denom -----
__global__ void k23_fused(const float* __restrict__ H, const float* __restrict__ ws,
                          float* __restrict__ e_out, float* __restrict__ ct,
                          float* __restrict__ denom) {
    __shared__ float4 s_q[FEAT / 4];
    __shared__ float4 s_part[4 * (FEAT / 4)];   // 4 waves x 25 float4
    __shared__ float s_den[4];
    int t = threadIdx.x;
    if (t < FEAT / 4) s_q[t] = ((const float4*)(ws + WS_Q))[t];
    __syncthreads();

    int i = blockIdx.x * 256 + t;
    float4 row[FEAT / 4];
    if (i < L) {
        const float4* h4 = (const float4*)H + (size_t)i * (FEAT / 4);
#pragma unroll
        for (int j = 0; j < FEAT / 4; ++j) row[j] = h4[j];
    } else {
#pragma unroll
        for (int j = 0; j < FEAT / 4; ++j) row[j] = make_float4(0.f, 0.f, 0.f, 0.f);
    }
    float acc = 0.f;
#pragma unroll
    for (int j = 0; j < FEAT / 4; ++j) {
        float4 b = s_q[j];
        acc += row[j].x * b.x + row[j].y * b.y + row[j].z * b.z + row[j].w * b.w;
    }
    float e = 0.f;
    if (i < L) {
        e = expf(acc);               // scores bounded well below 88 -> maxless softmax exact
        e_out[i] = e;
    }
    // scale row by e in-register
#pragma unroll
    for (int j = 0; j < FEAT / 4; ++j) {
        row[j].x *= e; row[j].y *= e; row[j].z *= e; row[j].w *= e;
    }
    // 64-lane butterfly sum of each component (all lanes end with wave total)
#pragma unroll
    for (int j = 0; j < FEAT / 4; ++j) {
#pragma unroll
        for (int o = 1; o < 64; o <<= 1) {
            row[j].x += __shfl_xor(row[j].x, o);
            row[j].y += __shfl_xor(row[j].y, o);
            row[j].z += __shfl_xor(row[j].z, o);
            row[j].w += __shfl_xor(row[j].w, o);
        }
    }
    float esum = e;
#pragma unroll
    for (int o = 1; o < 64; o <<= 1) esum += __shfl_xor(esum, o);

    int w = t >> 6, lane = t & 63;
#pragma unroll
    for (int j = 0; j < FEAT / 4; ++j)
        if (lane == j) s_part[w * (FEAT / 4) + j] = row[j];   // static index (all lanes hold totals)
    if (lane == 0) s_den[w] = esum;
    __syncthreads();

    if (t < FEAT) {
        const float* pf = (const float*)s_part;
        float v = pf[t] + pf[FEAT + t] + pf[2 * FEAT + t] + pf[3 * FEAT + t];
        atomicAdd(&ct[t], v);
    }
    if (t == 128) atomicAdd(denom, s_den[0] + s_den[1] + s_den[2] + s_den[3]);
}

// ---------------- K4: c_t /= denom ; e_t = sigmoid(l1) ; scale ----------------
__global__ void k4_et(const float* __restrict__ l1_W, const float* __restrict__ l1_b,
                      float* __restrict__ ws) {
    __shared__ float s_t[150];
    int t = threadIdx.x;
    float denom = ws[WS_DENOM];
    if (t < HID) s_t[t] = ws[WS_H + t];
    if (t < FEAT) s_t[HID + t] = ws[WS_CT + t] / denom;
    if (t == 0) ws[WS_SCALE] = ws[WS_P2] / denom;
    __syncthreads();
    if (t < 200) {
        float acc = l1_b[t];
        const float* w = l1_W + t * 150;
        for (int k = 0; k < 150; ++k) acc += w[k] * s_t[k];
        ws[WS_ET + t] = sigm(acc);
    }
}

// ---------------- K5: out[row] = p1*(l2_W[row].e_t + b) ; ext rows = 0 -------
__global__ void k5_vocab(const float* __restrict__ l2_W, const float* __restrict__ l2_b,
                         const float* __restrict__ ws, float* __restrict__ out) {
    __shared__ float4 s_e[50];
    __shared__ float s_p1;
    int t = threadIdx.x;
    if (t < 50) s_e[t] = ((const float4*)(ws + WS_ET))[t];
    if (t == 255) s_p1 = ws[WS_P1];
    __syncthreads();
    int w = t >> 6, lane = t & 63;
    int row = blockIdx.x * 4 + w;
    if (row < CQ) {
        float acc = 0.f;
        if (lane < 50) {
            float4 a = ((const float4*)l2_W)[(size_t)row * 50 + lane];
            float4 b = s_e[lane];
            acc = a.x * b.x + a.y * b.y + a.z * b.z + a.w * b.w;
        }
        for (int o = 32; o > 0; o >>= 1) acc += __shfl_down(acc, o);
        if (lane == 0) out[row] = s_p1 * (acc + l2_b[row]);
    } else if (row < NOUT) {
        if (lane == 0) out[row] = 0.f;
    }
}

// ---------------- K6: scatter-add pointer attention ----------------
__global__ void k6_scatter(const int* __restrict__ cont, const float* __restrict__ e,
                           const float* __restrict__ ws, float* __restrict__ out) {
    int i = blockIdx.x * blockDim.x + threadIdx.x;
    if (i < L) {
        float scale = ws[WS_SCALE];
        atomicAdd(&out[cont[i]], scale * e[i]);
    }
}

// ---------------- K7a: per-block max & sumexp partials ----------------
__global__ void k7a_partial(const float* __restrict__ outv, float* __restrict__ pm,
                            float* __restrict__ ps) {
    __shared__ float red[4];
    __shared__ float red2[4];
    int t = threadIdx.x;
    int chunk = (NOUT + gridDim.x - 1) / gridDim.x;
    int start = blockIdx.x * chunk;
    int end = min(start + chunk, NOUT);
    float m = -1e30f;
    for (int i = start + t; i < end; i += blockDim.x) m = fmaxf(m, outv[i]);
    for (int o = 32; o > 0; o >>= 1) m = fmaxf(m, __shfl_down(m, o));
    if ((t & 63) == 0) red[t >> 6] = m;
    __syncthreads();
    if (t == 0) red[0] = fmaxf(fmaxf(red[0], red[1]), fmaxf(red[2], red[3]));
    __syncthreads();
    m = red[0];
    float s = 0.f;
    for (int i = start + t; i < end; i += blockDim.x) s += expf(outv[i] - m);
    for (int o = 32; o > 0; o >>= 1) s += __shfl_down(s, o);
    if ((t & 63) == 0) red2[t >> 6] = s;
    __syncthreads();
    if (t == 0) { pm[blockIdx.x] = m; ps[blockIdx.x] = red2[0] + red2[1] + red2[2] + red2[3]; }
}

// ---------------- K7c: combine partials (redundant per thread) + final write --
__global__ void k7c_final(const float* __restrict__ outv, const float* __restrict__ pm,
                          const float* __restrict__ ps, float* __restrict__ dout) {
    int t = threadIdx.x;
    float gm = -1e30f;
    for (int b = 0; b < NB7; ++b) gm = fmaxf(gm, pm[b]);
    float s = 0.f;
    for (int b = 0; b < NB7; ++b) s += ps[b] * expf(pm[b] - gm);
    float lse = gm + logf(s);
    int j = blockIdx.x * blockDim.x + t;
    if (j < NOUT) dout[j] = outv[j] - lse;
}

extern "C" void kernel_launch(void* const* d_in, const int* in_sizes, int n_in,
                              void* d_out, int out_size, void* d_ws, size_t ws_size,
                              hipStream_t stream) {
    const float* H    = (const float*)d_in[0];
    const float* y    = (const float*)d_in[1];
    const float* h0   = (const float*)d_in[2];
    const float* c0   = (const float*)d_in[3];
    const int*   cont = (const int*)d_in[4];
    // d_in[5] = ext scalar (1000), hardcoded
    const float* W_ih = (const float*)d_in[6];
    const float* W_hh = (const float*)d_in[7];
    const float* b_ih = (const float*)d_in[8];
    const float* b_hh = (const float*)d_in[9];
    const float* w_h_W = (const float*)d_in[10];
    const float* w_h_b = (const float*)d_in[11];
    const float* l1_W = (const float*)d_in[12];
    const float* l1_b = (const float*)d_in[13];
    const float* l2_W = (const float*)d_in[14];
    const float* l2_b = (const float*)d_in[15];
    const float* l3_W = (const float*)d_in[16];
    const float* l3_b = (const float*)d_in[17];
    const float* l4_W = (const float*)d_in[18];
    const float* l4_b = (const float*)d_in[19];

    float* ws  = (float*)d_ws;
    float* out = (float*)d_out;

    k1_lstm<<<1, 256, 0, stream>>>(y, h0, c0, W_ih, W_hh, b_ih, b_hh,
                                   w_h_W, w_h_b, l3_W, l3_b, l4_W, l4_b, ws, out);

    k23_fused<<<(L + 255) / 256, 256, 0, stream>>>(H, ws, ws + WS_E, ws + WS_CT,
                                                   ws + WS_DENOM);

    k4_et<<<1, 256, 0, stream>>>(l1_W, l1_b, ws);

    k5_vocab<<<(NOUT + 3) / 4, 256, 0, stream>>>(l2_W, l2_b, ws, ws + WS_OUT);

    k6_scatter<<<(L + 255) / 256, 256, 0, stream>>>(cont, ws + WS_E, ws, ws + WS_OUT);

    k7a_partial<<<NB7, 256, 0, stream>>>(ws + WS_OUT, ws + WS_PM, ws + WS_PS);

    k7c_final<<<(NOUT + 255) / 256, 256, 0, stream>>>(ws + WS_OUT, ws + WS_PM, ws + WS_PS, out);
}

// Round 3
// 144.117 us; speedup vs baseline: 1.3661x; 1.0126x over previous
//
#include <hip/hip_runtime.h>
#include <math.h>

#define L 250000
#define FEAT 100
#define HID 50
#define HS 165
#define CQ 50257
#define EXTV 1000
#define NOUT (CQ + EXTV)   // 51257
#define NB7 128

#define TR 64          // rows per LDS tile
#define STRIDE4 33     // float4 per padded row (132 floats)
#define NBLK 1024      // k23 grid

// workspace float offsets
#define WS_Q     0      // 100 floats (16B-aligned: offset 0)
#define WS_P1    100
#define WS_P2    101
#define WS_SCALE 102    // p2/denom
#define WS_DENOM 103
#define WS_CT    104    // 100
#define WS_ET    204    // 200 (16B aligned: 204*4=816=51*16)
#define WS_H     404    // 50
#define WS_E     512    // 250000 (exp(score) per source position)
#define WS_OUT   250624 // 51257 (pre-logsoftmax extended vocab)
#define WS_PM    301952 // 128 partial maxes
#define WS_PS    302080 // 128 partial sums

__device__ __forceinline__ float sigm(float x) { return 1.f / (1.f + expf(-x)); }

// ---------------- K1: LSTM step + q + p1/p2 + accumulator init ----------------
__global__ void k1_lstm(const float* __restrict__ y, const float* __restrict__ h0,
                        const float* __restrict__ c0,
                        const float* __restrict__ W_ih, const float* __restrict__ W_hh,
                        const float* __restrict__ b_ih, const float* __restrict__ b_hh,
                        const float* __restrict__ w_h_W, const float* __restrict__ w_h_b,
                        const float* __restrict__ l3_W, const float* __restrict__ l3_b,
                        const float* __restrict__ l4_W, const float* __restrict__ l4_b,
                        float* __restrict__ ws, float* __restrict__ out) {
    __shared__ float s_y[HS], s_h[HID], s_c[HID], s_g[4 * HID], s_hn[HID];
    int t = threadIdx.x;
    if (t < HS) s_y[t] = y[t];
    if (t < HID) { s_h[t] = h0[t]; s_c[t] = c0[t]; }
    __syncthreads();
    if (t < 4 * HID) {
        float acc = b_ih[t] + b_hh[t];
        const float* wi = W_ih + t * HS;
        for (int k = 0; k < HS; ++k) acc += wi[k] * s_y[k];
        const float* wh = W_hh + t * HID;
        for (int k = 0; k < HID; ++k) acc += wh[k] * s_h[k];
        s_g[t] = acc;
    }
    __syncthreads();
    if (t < HID) {
        float ig = sigm(s_g[t]);
        float fg = sigm(s_g[HID + t]);
        float gg = tanhf(s_g[2 * HID + t]);
        float og = sigm(s_g[3 * HID + t]);
        float cn = fg * s_c[t] + ig * gg;
        float hn = og * tanhf(cn);
        s_hn[t] = hn;
        ws[WS_H + t] = hn;
        out[NOUT + t] = hn;          // h_new output
        out[NOUT + HID + t] = cn;    // c_new output
    }
    __syncthreads();
    if (t < FEAT) {
        float acc = w_h_b[t];
        const float* w = w_h_W + t * HID;
        for (int k = 0; k < HID; ++k) acc += w[k] * s_hn[k];
        ws[WS_Q + t] = acc;
        ws[WS_CT + t] = 0.f;         // zero context accumulator
    }
    if (t == 200) {
        float acc = l3_b[0];
        for (int k = 0; k < HID; ++k) acc += l3_W[k] * s_hn[k];
        ws[WS_P1] = sigm(acc);
    }
    if (t == 201) {
        float acc = l4_b[0];
        for (int k = 0; k < HID; ++k) acc += l4_W[k] * s_hn[k];
        ws[WS_P2] = sigm(acc);
    }
    if (t == 202) ws[WS_DENOM] = 0.f;
}

// ------- K23: LDS-tiled single pass over H: e, denom, ct -----
__global__ void __launch_bounds__(256, 2)
k23_fused(const float* __restrict__ H, const float* __restrict__ ws,
          float* __restrict__ e_out, float* __restrict__ ct,
          float* __restrict__ denom) {
    __shared__ float4 s_tile[TR * STRIDE4];   // 33792 B
    __shared__ float4 s_q[26];
    __shared__ float s_e[TR];
    __shared__ float s_red[64];
    __shared__ float s_col[2][FEAT];
    int t = threadIdx.x;
    if (t < 25) s_q[t] = ((const float4*)(ws + WS_Q))[t];
    if (t == 25) s_q[25] = make_float4(0.f, 0.f, 0.f, 0.f);
    if (t < TR) s_tile[t * STRIDE4 + 25] = make_float4(0.f, 0.f, 0.f, 0.f); // zero pad cg25

    int per = (L + NBLK - 1) / NBLK;     // 245
    int start = blockIdx.x * per;
    int end = min(start + per, L);

    int c = t & 127, g = t >> 7;
    float cacc = 0.f;       // phase-3 column partial (col c, row-group g)
    float dacc = 0.f;       // denom partial (threads t<128, t even)

    __syncthreads();

    const float4* H4 = (const float4*)H;
    for (int t0 = start; t0 < end; t0 += TR) {
        int vr = min(TR, end - t0);      // valid rows this tile (first tile always full)
        int nf = vr * 25;
        // ---- phase 1: reg-staged coalesced load (all loads issued before writes)
        float4 vv[7];
#pragma unroll
        for (int j = 0; j < 7; ++j) {
            int fi = t + j * 256;
            if (fi < nf) vv[j] = H4[(size_t)t0 * 25 + fi];
        }
#pragma unroll
        for (int j = 0; j < 7; ++j) {
            int fi = t + j * 256;
            if (fi < nf) {
                int row = fi / 25, cg = fi - row * 25;
                s_tile[row * STRIDE4 + cg] = vv[j];
            }
        }
        __syncthreads();
        // ---- phase 2: dot per row (2 threads/row), e = exp(dot)
        if (t < 2 * TR) {
            int row = t >> 1, half = t & 1;
            float acc = 0.f;
            const float4* rp = &s_tile[row * STRIDE4 + half * 13];
            const float4* qp = &s_q[half * 13];
#pragma unroll
            for (int j = 0; j < 13; ++j) {
                float4 a = rp[j], b = qp[j];
                acc += a.x * b.x + a.y * b.y + a.z * b.z + a.w * b.w;
            }
            acc += __shfl_xor(acc, 1);
            if (half == 0) {
                float e = 0.f;
                if (row < vr) { e = expf(acc); e_out[t0 + row] = e; dacc += e; }
                s_e[row] = e;   // 0 for invalid rows -> phase 3 contributes 0
            }
        }
        __syncthreads();
        // ---- phase 3: column-parallel ct partials
        if (c < FEAT) {
            const float* base = (const float*)s_tile;
#pragma unroll
            for (int k = 0; k < 32; ++k) {
                int r = g * 32 + k;
                cacc += s_e[r] * base[r * (4 * STRIDE4) + c];
            }
        }
        __syncthreads();
    }
    // ---- block combine
    if (c < FEAT) s_col[g][c] = cacc;
    if (t < 128 && (t & 1) == 0) s_red[t >> 1] = dacc;
    __syncthreads();
    if (t < FEAT) atomicAdd(&ct[t], s_col[0][t] + s_col[1][t]);
    if (t < 64) {
        float v = s_red[t];
#pragma unroll
        for (int o = 1; o < 64; o <<= 1) v += __shfl_xor(v, o);
        if (t == 0) atomicAdd(denom, v);
    }
}

// ---------------- K4: c_t /= denom ; e_t = sigmoid(l1) ; scale ----------------
__global__ void k4_et(const float* __restrict__ l1_W, const float* __restrict__ l1_b,
                      float* __restrict__ ws) {
    __shared__ float s_t[150];
    int t = threadIdx.x;
    float denom = ws[WS_DENOM];
    if (t < HID) s_t[t] = ws[WS_H + t];
    if (t < FEAT) s_t[HID + t] = ws[WS_CT + t] / denom;
    if (t == 0) ws[WS_SCALE] = ws[WS_P2] / denom;
    __syncthreads();
    if (t < 200) {
        float acc = l1_b[t];
        const float* w = l1_W + t * 150;
        for (int k = 0; k < 150; ++k) acc += w[k] * s_t[k];
        ws[WS_ET + t] = sigm(acc);
    }
}

// ---------------- K5: out[row] = p1*(l2_W[row].e_t + b) ; ext rows = 0 -------
__global__ void k5_vocab(const float* __restrict__ l2_W, const float* __restrict__ l2_b,
                         const float* __restrict__ ws, float* __restrict__ out) {
    __shared__ float4 s_e[50];
    __shared__ float s_p1;
    int t = threadIdx.x;
    if (t < 50) s_e[t] = ((const float4*)(ws + WS_ET))[t];
    if (t == 255) s_p1 = ws[WS_P1];
    __syncthreads();
    int w = t >> 6, lane = t & 63;
    int row = blockIdx.x * 4 + w;
    if (row < CQ) {
        float acc = 0.f;
        if (lane < 50) {
            float4 a = ((const float4*)l2_W)[(size_t)row * 50 + lane];
            float4 b = s_e[lane];
            acc = a.x * b.x + a.y * b.y + a.z * b.z + a.w * b.w;
        }
        for (int o = 32; o > 0; o >>= 1) acc += __shfl_down(acc, o);
        if (lane == 0) out[row] = s_p1 * (acc + l2_b[row]);
    } else if (row < NOUT) {
        if (lane == 0) out[row] = 0.f;
    }
}

// ---------------- K6: scatter-add pointer attention ----------------
__global__ void k6_scatter(const int* __restrict__ cont, const float* __restrict__ e,
                           const float* __restrict__ ws, float* __restrict__ out) {
    int i = blockIdx.x * blockDim.x + threadIdx.x;
    if (i < L) {
        float scale = ws[WS_SCALE];
        atomicAdd(&out[cont[i]], scale * e[i]);
    }
}

// ---------------- K7a: per-block max & sumexp partials ----------------
__global__ void k7a_partial(const float* __restrict__ outv, float* __restrict__ pm,
                            float* __restrict__ ps) {
    __shared__ float red[4];
    __shared__ float red2[4];
    int t = threadIdx.x;
    int chunk = (NOUT + gridDim.x - 1) / gridDim.x;
    int start = blockIdx.x * chunk;
    int end = min(start + chunk, NOUT);
    float m = -1e30f;
    for (int i = start + t; i < end; i += blockDim.x) m = fmaxf(m, outv[i]);
    for (int o = 32; o > 0; o >>= 1) m = fmaxf(m, __shfl_down(m, o));
    if ((t & 63) == 0) red[t >> 6] = m;
    __syncthreads();
    if (t == 0) red[0] = fmaxf(fmaxf(red[0], red[1]), fmaxf(red[2], red[3]));
    __syncthreads();
    m = red[0];
    float s = 0.f;
    for (int i = start + t; i < end; i += blockDim.x) s += expf(outv[i] - m);
    for (int o = 32; o > 0; o >>= 1) s += __shfl_down(s, o);
    if ((t & 63) == 0) red2[t >> 6] = s;
    __syncthreads();
    if (t == 0) { pm[blockIdx.x] = m; ps[blockIdx.x] = red2[0] + red2[1] + red2[2] + red2[3]; }
}

// ---------------- K7c: combine partials (redundant per thread) + final write --
__global__ void k7c_final(const float* __restrict__ outv, const float* __restrict__ pm,
                          const float* __restrict__ ps, float* __restrict__ dout) {
    int t = threadIdx.x;
    float gm = -1e30f;
    for (int b = 0; b < NB7; ++b) gm = fmaxf(gm, pm[b]);
    float s = 0.f;
    for (int b = 0; b < NB7; ++b) s += ps[b] * expf(pm[b] - gm);
    float lse = gm + logf(s);
    int j = blockIdx.x * blockDim.x + t;
    if (j < NOUT) dout[j] = outv[j] - lse;
}

extern "C" void kernel_launch(void* const* d_in, const int* in_sizes, int n_in,
                              void* d_out, int out_size, void* d_ws, size_t ws_size,
                              hipStream_t stream) {
    const float* H    = (const float*)d_in[0];
    const float* y    = (const float*)d_in[1];
    const float* h0   = (const float*)d_in[2];
    const float* c0   = (const float*)d_in[3];
    const int*   cont = (const int*)d_in[4];
    // d_in[5] = ext scalar (1000), hardcoded
    const float* W_ih = (const float*)d_in[6];
    const float* W_hh = (const float*)d_in[7];
    const float* b_ih = (const float*)d_in[8];
    const float* b_hh = (const float*)d_in[9];
    const float* w_h_W = (const float*)d_in[10];
    const float* w_h_b = (const float*)d_in[11];
    const float* l1_W = (const float*)d_in[12];
    const float* l1_b = (const float*)d_in[13];
    const float* l2_W = (const float*)d_in[14];
    const float* l2_b = (const float*)d_in[15];
    const float* l3_W = (const float*)d_in[16];
    const float* l3_b = (const float*)d_in[17];
    const float* l4_W = (const float*)d_in[18];
    const float* l4_b = (const float*)d_in[19];

    float* ws  = (float*)d_ws;
    float* out = (float*)d_out;

    k1_lstm<<<1, 256, 0, stream>>>(y, h0, c0, W_ih, W_hh, b_ih, b_hh,
                                   w_h_W, w_h_b, l3_W, l3_b, l4_W, l4_b, ws, out);

    k23_fused<<<NBLK, 256, 0, stream>>>(H, ws, ws + WS_E, ws + WS_CT, ws + WS_DENOM);

    k4_et<<<1, 256, 0, stream>>>(l1_W, l1_b, ws);

    k5_vocab<<<(NOUT + 3) / 4, 256, 0, stream>>>(l2_W, l2_b, ws, ws + WS_OUT);

    k6_scatter<<<(L + 255) / 256, 256, 0, stream>>>(cont, ws + WS_E, ws, ws + WS_OUT);

    k7a_partial<<<NB7, 256, 0, stream>>>(ws + WS_OUT, ws + WS_PM, ws + WS_PS);

    k7c_final<<<(NOUT + 255) / 256, 256, 0, stream>>>(ws + WS_OUT, ws + WS_PM, ws + WS_PS, out);
}

// Round 4
// 108.991 us; speedup vs baseline: 1.8064x; 1.3223x over previous
//
#include <hip/hip_runtime.h>
#include <math.h>

#define L 250000
#define FEAT 100
#define HID 50
#define HS 165
#define CQ 50257
#define EXTV 1000
#define NOUT (CQ + EXTV)   // 51257
#define NB7 128

#define TR 64                       // rows per LDS tile
#define TILE_F4 (TR * 25)           // 1600 float4 per tile (linear, no pad)
#define ROWS_PER_BLK 256
#define NBLK ((L + ROWS_PER_BLK - 1) / ROWS_PER_BLK)   // 977

// workspace float offsets
#define WS_Q     0      // 100 floats (16B-aligned: offset 0)
#define WS_P1    100
#define WS_P2    101
#define WS_SCALE 102    // p2/denom
#define WS_DENOM 103
#define WS_CT    104    // 100
#define WS_ET    204    // 200 (16B aligned: 204*4=816=51*16)
#define WS_H     404    // 50
#define WS_E     512    // 250000 (exp(score) per source position)
#define WS_OUT   250624 // 51257 (pre-logsoftmax extended vocab)
#define WS_PM    301952 // 128 partial maxes
#define WS_PS    302080 // 128 partial sums

__device__ __forceinline__ float sigm(float x) { return 1.f / (1.f + expf(-x)); }

// async global->LDS, 16B per lane; LDS dest must be wave-uniform base (HW adds lane*16)
__device__ __forceinline__ void async16(void* lds, const void* gsrc) {
    __builtin_amdgcn_global_load_lds(
        (__attribute__((address_space(1))) void*)gsrc,
        (__attribute__((address_space(3))) void*)lds,
        16, 0, 0);
}

// ---------------- K1: LSTM step + q + p1/p2 + accumulator init ----------------
__global__ void k1_lstm(const float* __restrict__ y, const float* __restrict__ h0,
                        const float* __restrict__ c0,
                        const float* __restrict__ W_ih, const float* __restrict__ W_hh,
                        const float* __restrict__ b_ih, const float* __restrict__ b_hh,
                        const float* __restrict__ w_h_W, const float* __restrict__ w_h_b,
                        const float* __restrict__ l3_W, const float* __restrict__ l3_b,
                        const float* __restrict__ l4_W, const float* __restrict__ l4_b,
                        float* __restrict__ ws, float* __restrict__ out) {
    __shared__ float s_y[HS], s_h[HID], s_c[HID], s_g[4 * HID], s_hn[HID];
    int t = threadIdx.x;
    if (t < HS) s_y[t] = y[t];
    if (t < HID) { s_h[t] = h0[t]; s_c[t] = c0[t]; }
    __syncthreads();
    if (t < 4 * HID) {
        float acc = b_ih[t] + b_hh[t];
        const float* wi = W_ih + t * HS;
        for (int k = 0; k < HS; ++k) acc += wi[k] * s_y[k];
        const float* wh = W_hh + t * HID;
        for (int k = 0; k < HID; ++k) acc += wh[k] * s_h[k];
        s_g[t] = acc;
    }
    __syncthreads();
    if (t < HID) {
        float ig = sigm(s_g[t]);
        float fg = sigm(s_g[HID + t]);
        float gg = tanhf(s_g[2 * HID + t]);
        float og = sigm(s_g[3 * HID + t]);
        float cn = fg * s_c[t] + ig * gg;
        float hn = og * tanhf(cn);
        s_hn[t] = hn;
        ws[WS_H + t] = hn;
        out[NOUT + t] = hn;          // h_new output
        out[NOUT + HID + t] = cn;    // c_new output
    }
    __syncthreads();
    if (t < FEAT) {
        float acc = w_h_b[t];
        const float* w = w_h_W + t * HID;
        for (int k = 0; k < HID; ++k) acc += w[k] * s_hn[k];
        ws[WS_Q + t] = acc;
        ws[WS_CT + t] = 0.f;         // zero context accumulator
    }
    if (t == 200) {
        float acc = l3_b[0];
        for (int k = 0; k < HID; ++k) acc += l3_W[k] * s_hn[k];
        ws[WS_P1] = sigm(acc);
    }
    if (t == 201) {
        float acc = l4_b[0];
        for (int k = 0; k < HID; ++k) acc += l4_W[k] * s_hn[k];
        ws[WS_P2] = sigm(acc);
    }
    if (t == 202) ws[WS_DENOM] = 0.f;
}

// ------- K23: LDS-tiled single pass over H via global_load_lds: e, denom, ct --
__global__ void __launch_bounds__(256)
k23_fused(const float* __restrict__ H, const float* __restrict__ ws,
          float* __restrict__ e_out, float* __restrict__ ct,
          float* __restrict__ denom) {
    __shared__ float4 s_lin[TILE_F4];   // 25600 B, linear row-major (25 f4 per row)
    __shared__ float4 s_q[25];
    __shared__ float s_e[TR];
    __shared__ float s_red[64];
    __shared__ float s_col[2][FEAT];
    int t = threadIdx.x;
    if (t < 25) s_q[t] = ((const float4*)(ws + WS_Q))[t];

    int start = blockIdx.x * ROWS_PER_BLK;
    int end = min(start + ROWS_PER_BLK, L);

    int c = t & 127, g = t >> 7;
    int wbase = t & 192;      // wave index * 64 (wave-uniform)
    int lane = t & 63;
    float cacc = 0.f;         // phase-3 column partial
    float dacc = 0.f;         // denom partial (q==0 threads)

    const float4* H4 = (const float4*)H;
    const size_t gmax = (size_t)L * 25 - 1;

    for (int t0 = start; t0 < end; t0 += TR) {
        int vr = min(TR, end - t0);
        // ---- phase 1: async global->LDS (linear), zero VGPR staging
        size_t gbase = (size_t)t0 * 25;
#pragma unroll
        for (int j = 0; j < 7; ++j) {
            int chunk = j * 256 + wbase;           // wave-uniform LDS base (f4 units)
            if (chunk < TILE_F4) {                  // uniform per wave
                size_t gi = gbase + chunk + lane;   // per-lane global address
                if (gi > gmax) gi = gmax;           // clamp (dup data, zeroed via s_e)
                async16(&s_lin[chunk], H4 + gi);
            }
        }
        asm volatile("s_waitcnt vmcnt(0)" ::: "memory");
        __syncthreads();
        // ---- phase 2: dot per row (4 threads/row, 25 scalars each), e = exp(dot)
        {
            int row = t >> 2, q = t & 3;
            const float* rp = (const float*)s_lin + row * FEAT + q * 25;
            const float* qp = (const float*)s_q + q * 25;
            float acc = 0.f;
#pragma unroll
            for (int k = 0; k < 25; ++k) acc += rp[k] * qp[k];
            acc += __shfl_xor(acc, 1);
            acc += __shfl_xor(acc, 2);
            if (q == 0) {
                float e = 0.f;
                if (row < vr) { e = expf(acc); e_out[t0 + row] = e; dacc += e; }
                s_e[row] = e;   // 0 for invalid rows -> phase 3 contributes 0
            }
        }
        __syncthreads();
        // ---- phase 3: column-parallel ct partials (consecutive cols: conflict-free)
        if (c < FEAT) {
            const float* base = (const float*)s_lin;
#pragma unroll
            for (int k = 0; k < 32; ++k) {
                int r = g * 32 + k;
                cacc += s_e[r] * base[r * FEAT + c];
            }
        }
        __syncthreads();
    }
    // ---- block combine
    if (c < FEAT) s_col[g][c] = cacc;
    if ((t & 3) == 0) s_red[t >> 2] = dacc;
    __syncthreads();
    if (t < FEAT) atomicAdd(&ct[t], s_col[0][t] + s_col[1][t]);
    if (t < 64) {
        float v = s_red[t];
#pragma unroll
        for (int o = 1; o < 64; o <<= 1) v += __shfl_xor(v, o);
        if (t == 0) atomicAdd(denom, v);
    }
}

// ---------------- K4: c_t /= denom ; e_t = sigmoid(l1) ; scale ----------------
__global__ void k4_et(const float* __restrict__ l1_W, const float* __restrict__ l1_b,
                      float* __restrict__ ws) {
    __shared__ float s_t[150];
    int t = threadIdx.x;
    float denom = ws[WS_DENOM];
    if (t < HID) s_t[t] = ws[WS_H + t];
    if (t < FEAT) s_t[HID + t] = ws[WS_CT + t] / denom;
    if (t == 0) ws[WS_SCALE] = ws[WS_P2] / denom;
    __syncthreads();
    if (t < 200) {
        float acc = l1_b[t];
        const float* w = l1_W + t * 150;
        for (int k = 0; k < 150; ++k) acc += w[k] * s_t[k];
        ws[WS_ET + t] = sigm(acc);
    }
}

// ---------------- K5: out[row] = p1*(l2_W[row].e_t + b) ; ext rows = 0 -------
__global__ void k5_vocab(const float* __restrict__ l2_W, const float* __restrict__ l2_b,
                         const float* __restrict__ ws, float* __restrict__ out) {
    __shared__ float4 s_e[50];
    __shared__ float s_p1;
    int t = threadIdx.x;
    if (t < 50) s_e[t] = ((const float4*)(ws + WS_ET))[t];
    if (t == 255) s_p1 = ws[WS_P1];
    __syncthreads();
    int w = t >> 6, lane = t & 63;
    int row = blockIdx.x * 4 + w;
    if (row < CQ) {
        float acc = 0.f;
        if (lane < 50) {
            float4 a = ((const float4*)l2_W)[(size_t)row * 50 + lane];
            float4 b = s_e[lane];
            acc = a.x * b.x + a.y * b.y + a.z * b.z + a.w * b.w;
        }
        for (int o = 32; o > 0; o >>= 1) acc += __shfl_down(acc, o);
        if (lane == 0) out[row] = s_p1 * (acc + l2_b[row]);
    } else if (row < NOUT) {
        if (lane == 0) out[row] = 0.f;
    }
}

// ---------------- K6: scatter-add pointer attention ----------------
__global__ void k6_scatter(const int* __restrict__ cont, const float* __restrict__ e,
                           const float* __restrict__ ws, float* __restrict__ out) {
    int i = blockIdx.x * blockDim.x + threadIdx.x;
    if (i < L) {
        float scale = ws[WS_SCALE];
        atomicAdd(&out[cont[i]], scale * e[i]);
    }
}

// ---------------- K7a: per-block max & sumexp partials ----------------
__global__ void k7a_partial(const float* __restrict__ outv, float* __restrict__ pm,
                            float* __restrict__ ps) {
    __shared__ float red[4];
    __shared__ float red2[4];
    int t = threadIdx.x;
    int chunk = (NOUT + gridDim.x - 1) / gridDim.x;
    int start = blockIdx.x * chunk;
    int end = min(start + chunk, NOUT);
    float m = -1e30f;
    for (int i = start + t; i < end; i += blockDim.x) m = fmaxf(m, outv[i]);
    for (int o = 32; o > 0; o >>= 1) m = fmaxf(m, __shfl_down(m, o));
    if ((t & 63) == 0) red[t >> 6] = m;
    __syncthreads();
    if (t == 0) red[0] = fmaxf(fmaxf(red[0], red[1]), fmaxf(red[2], red[3]));
    __syncthreads();
    m = red[0];
    float s = 0.f;
    for (int i = start + t; i < end; i += blockDim.x) s += expf(outv[i] - m);
    for (int o = 32; o > 0; o >>= 1) s += __shfl_down(s, o);
    if ((t & 63) == 0) red2[t >> 6] = s;
    __syncthreads();
    if (t == 0) { pm[blockIdx.x] = m; ps[blockIdx.x] = red2[0] + red2[1] + red2[2] + red2[3]; }
}

// ---------------- K7c: combine partials (redundant per thread) + final write --
__global__ void k7c_final(const float* __restrict__ outv, const float* __restrict__ pm,
                          const float* __restrict__ ps, float* __restrict__ dout) {
    int t = threadIdx.x;
    float gm = -1e30f;
    for (int b = 0; b < NB7; ++b) gm = fmaxf(gm, pm[b]);
    float s = 0.f;
    for (int b = 0; b < NB7; ++b) s += ps[b] * expf(pm[b] - gm);
    float lse = gm + logf(s);
    int j = blockIdx.x * blockDim.x + t;
    if (j < NOUT) dout[j] = outv[j] - lse;
}

extern "C" void kernel_launch(void* const* d_in, const int* in_sizes, int n_in,
                              void* d_out, int out_size, void* d_ws, size_t ws_size,
                              hipStream_t stream) {
    const float* H    = (const float*)d_in[0];
    const float* y    = (const float*)d_in[1];
    const float* h0   = (const float*)d_in[2];
    const float* c0   = (const float*)d_in[3];
    const int*   cont = (const int*)d_in[4];
    // d_in[5] = ext scalar (1000), hardcoded
    const float* W_ih = (const float*)d_in[6];
    const float* W_hh = (const float*)d_in[7];
    const float* b_ih = (const float*)d_in[8];
    const float* b_hh = (const float*)d_in[9];
    const float* w_h_W = (const float*)d_in[10];
    const float* w_h_b = (const float*)d_in[11];
    const float* l1_W = (const float*)d_in[12];
    const float* l1_b = (const float*)d_in[13];
    const float* l2_W = (const float*)d_in[14];
    const float* l2_b = (const float*)d_in[15];
    const float* l3_W = (const float*)d_in[16];
    const float* l3_b = (const float*)d_in[17];
    const float* l4_W = (const float*)d_in[18];
    const float* l4_b = (const float*)d_in[19];

    float* ws  = (float*)d_ws;
    float* out = (float*)d_out;

    k1_lstm<<<1, 256, 0, stream>>>(y, h0, c0, W_ih, W_hh, b_ih, b_hh,
                                   w_h_W, w_h_b, l3_W, l3_b, l4_W, l4_b, ws, out);

    k23_fused<<<NBLK, 256, 0, stream>>>(H, ws, ws + WS_E, ws + WS_CT, ws + WS_DENOM);

    k4_et<<<1, 256, 0, stream>>>(l1_W, l1_b, ws);

    k5_vocab<<<(NOUT + 3) / 4, 256, 0, stream>>>(l2_W, l2_b, ws, ws + WS_OUT);

    k6_scatter<<<(L + 255) / 256, 256, 0, stream>>>(cont, ws + WS_E, ws, ws + WS_OUT);

    k7a_partial<<<NB7, 256, 0, stream>>>(ws + WS_OUT, ws + WS_PM, ws + WS_PS);

    k7c_final<<<(NOUT + 255) / 256, 256, 0, stream>>>(ws + WS_OUT, ws + WS_PM, ws + WS_PS, out);
}